// Round 5
// baseline (1248.029 us; speedup 1.0000x reference)
//
#include <hip/hip_runtime.h>

#define NN 50000
#define NE 800000
#define D  128
#define NB 3125        // node buckets of 16 (16*3125 == 50000)
#define NG 8           // sub-slabs per bucket (XCD-affinity groups)
#define CAPG 128       // capacity per (bucket,group); Poisson(64)+8sigma

// ---- new-path ws layout (bytes) ----
#define OFF_SLAB 0                    // int2[NB*NG*CAPG]   25,600,000
#define OFF_BCNT 25600000             // int[NB*NG]            100,000
#define OFF_XW   25700096             // ushort[NN*D]       12,800,000
#define NEED_NEW (OFF_XW + (size_t)NN * D * 2)   // 38,500,096

// ---- fallback (R3 path B) ws layout ----
#define OFF_CNT  0
#define OFF_ROW  200704
#define OFF_CUR  401408
#define OFF_CSR  602112               // int2[2E] 12.8 MB

__device__ __forceinline__ float bf_lo(unsigned int v) { return __uint_as_float(v << 16); }
__device__ __forceinline__ float bf_hi(unsigned int v) { return __uint_as_float(v & 0xffff0000u); }

// ---------------------------------------------------------------------------
// K1: XW = X @ W, bf16 RNE output (packed). Block owns 16 rows; W in LDS.
// ---------------------------------------------------------------------------
__global__ __launch_bounds__(256) void gc_gemm_bf16(
    const float* __restrict__ src, unsigned short* __restrict__ dst,
    const float* __restrict__ Wm)
{
    __shared__ float Ws[D * D];
    __shared__ float axs[16 * D];
    const int tid = threadIdx.x;
    const int col = tid & 127;
    const int ty  = tid >> 7;
    const int rbase = blockIdx.x * 16;

    const float4* W4  = reinterpret_cast<const float4*>(Wm);
    float4*       Ws4 = reinterpret_cast<float4*>(Ws);
    #pragma unroll
    for (int i = 0; i < 16; ++i) Ws4[tid + i * 256] = W4[tid + i * 256];

    const float4* A4   = reinterpret_cast<const float4*>(src + (size_t)rbase * D);
    float4*       axs4 = reinterpret_cast<float4*>(axs);
    #pragma unroll
    for (int i = 0; i < 2; ++i) axs4[tid + i * 256] = A4[tid + i * 256];
    __syncthreads();

    float acc[8];
    #pragma unroll
    for (int i = 0; i < 8; ++i) acc[i] = 0.f;

    for (int k = 0; k < D; ++k) {
        float wv = Ws[k * D + col];
        #pragma unroll
        for (int i = 0; i < 8; ++i)
            acc[i] = fmaf(axs[(ty * 8 + i) * D + k], wv, acc[i]);
    }

    #pragma unroll
    for (int i = 0; i < 8; ++i) {
        unsigned int bb = __float_as_uint(acc[i]);
        unsigned int r  = (bb + 0x7fffu + ((bb >> 16) & 1u)) >> 16;   // RNE
        dst[(size_t)(rbase + ty * 8 + i) * D + col] = (unsigned short)r;
    }
}

// ---------------------------------------------------------------------------
// K2: bin directed edges into per-(bucket, group) slabs. g = blockIdx&7 keeps
// each sub-slab's appends on (heuristically) one XCD -> clustered writebacks.
// Entry packs (src:16 | dst_local:4) in .x, weight bits in .y.
// ---------------------------------------------------------------------------
__global__ __launch_bounds__(256) void gc_bin(
    const int2* __restrict__ edges, const float* __restrict__ wts,
    int* __restrict__ bcnt, int2* __restrict__ slab)
{
    int e = blockIdx.x * 256 + threadIdx.x;
    if (e >= NE) return;
    int g = blockIdx.x & (NG - 1);
    int2 p = edges[e];
    int wb = __float_as_int(wts[e]);
    {
        int b = p.y >> 4;                       // contributes to row p.y
        int pos = atomicAdd(bcnt + b * NG + g, 1);
        if (pos < CAPG)
            slab[((size_t)b * NG + g) * CAPG + pos] =
                make_int2(p.x | ((p.y & 15) << 16), wb);
    }
    {
        int b = p.x >> 4;                       // reverse direction
        int pos = atomicAdd(bcnt + b * NG + g, 1);
        if (pos < CAPG)
            slab[((size_t)b * NG + g) * CAPG + pos] =
                make_int2(p.y | ((p.x & 15) << 16), wb);
    }
}

// ---------------------------------------------------------------------------
// K3: per-bucket accumulate. 1 block per bucket; 16-row fp32 tile in LDS via
// ds_add_f32; gathers bf16 XW rows; fused degree + normalize; coalesced out.
// ---------------------------------------------------------------------------
__global__ __launch_bounds__(256) void gc_acc(
    const int* __restrict__ bcnt, const int2* __restrict__ slab,
    const unsigned int* __restrict__ XW, float* __restrict__ out)
{
    __shared__ float acc[16 * D];
    __shared__ float degw[16];
    const int tid  = threadIdx.x;
    const int lane = tid & 63;
    const int wv   = tid >> 6;
    const int b    = blockIdx.x;

    for (int i = tid; i < 16 * D; i += 256) acc[i] = 0.f;
    if (tid < 16) degw[tid] = 0.f;
    __syncthreads();

    for (int g = 0; g < NG; ++g) {
        int cnt = bcnt[b * NG + g];
        cnt = cnt < CAPG ? cnt : CAPG;
        const int2* s = slab + ((size_t)b * NG + g) * CAPG;
        for (int j = wv; j < cnt; j += 4) {     // wave-uniform -> scalar loads
            int2  ent = s[j];
            int   src = ent.x & 0xffff;
            int   dl  = (ent.x >> 16) & 15;
            float w   = __int_as_float(ent.y);
            unsigned int v = XW[(size_t)src * 64 + lane];  // coalesced 256B
            atomicAdd(&acc[dl * D + 2 * lane],     w * bf_lo(v));
            atomicAdd(&acc[dl * D + 2 * lane + 1], w * bf_hi(v));
            if (lane == 0) atomicAdd(&degw[dl], w);
        }
    }
    __syncthreads();

    #pragma unroll
    for (int r = wv; r < 16; r += 4) {
        float dg  = degw[r];
        float inv = dg > 0.f ? 1.f / dg : 0.f;
        float2 o;
        o.x = acc[r * D + 2 * lane] * inv;
        o.y = acc[r * D + 2 * lane + 1] * inv;
        reinterpret_cast<float2*>(out)[((size_t)b * 16 + r) * 64 + lane] = o;
    }
}

// ======================= fallback path (R3 path B) =========================
__global__ __launch_bounds__(256) void gc_hist(
    const int2* __restrict__ edges, int* __restrict__ counts)
{
    int e = blockIdx.x * 256 + threadIdx.x;
    if (e >= NE) return;
    int2 p = edges[e];
    atomicAdd(counts + p.x, 1);
    atomicAdd(counts + p.y, 1);
}

__global__ __launch_bounds__(1024) void gc_scan(
    const int* __restrict__ counts, int* __restrict__ row_start,
    int* __restrict__ cursor)
{
    const int CHUNK = (NN + 1023) / 1024;
    __shared__ int part[1024];
    int t = threadIdx.x;
    int lo = t * CHUNK, hi = min(lo + CHUNK, NN);
    int s = 0;
    for (int i = lo; i < hi; ++i) s += counts[i];
    part[t] = s;
    __syncthreads();
    for (int off = 1; off < 1024; off <<= 1) {
        int v = (t >= off) ? part[t - off] : 0;
        __syncthreads();
        part[t] += v;
        __syncthreads();
    }
    int run = part[t] - s;
    for (int i = lo; i < hi; ++i) {
        int c = counts[i];
        row_start[i] = run;
        cursor[i]    = run;
        run += c;
    }
    if (t == 1023) row_start[NN] = part[1023];
}

__global__ __launch_bounds__(256) void gc_fill(
    const int2* __restrict__ edges, const float* __restrict__ wts,
    int* __restrict__ cursor, int2* __restrict__ csr)
{
    int e = blockIdx.x * 256 + threadIdx.x;
    if (e >= NE) return;
    int2 p = edges[e];
    int wb = __float_as_int(wts[e]);
    int pos = atomicAdd(cursor + p.y, 1);
    csr[pos] = make_int2(p.x, wb);
    pos = atomicAdd(cursor + p.x, 1);
    csr[pos] = make_int2(p.y, wb);
}

__global__ __launch_bounds__(256) void gc_gather_f32(
    const int* __restrict__ row_start, const int2* __restrict__ csr,
    const float* __restrict__ F, float* __restrict__ out)
{
    int wid  = (blockIdx.x * 256 + threadIdx.x) >> 6;
    int lane = threadIdx.x & 63;
    if (wid >= NN) return;
    int j   = row_start[wid];
    int end = row_start[wid + 1];
    const float2* F2 = reinterpret_cast<const float2*>(F);
    float ax = 0.f, ay = 0.f, dw = 0.f;
    for (; j < end; ++j) {
        int2  cw = csr[j];
        float w  = __int_as_float(cw.y);
        float2 xv = F2[(size_t)cw.x * 64 + lane];
        ax = fmaf(w, xv.x, ax);
        ay = fmaf(w, xv.y, ay);
        dw += w;
    }
    float inv = dw > 0.f ? 1.f / dw : 0.f;
    float2 r; r.x = ax * inv; r.y = ay * inv;
    reinterpret_cast<float2*>(out)[(size_t)wid * 64 + lane] = r;
}

__global__ __launch_bounds__(256) void gc_gemm_f32(
    const float* __restrict__ src, float* __restrict__ dst,
    const float* __restrict__ Wm)
{
    __shared__ float Ws[D * D];
    __shared__ float axs[16 * D];
    const int tid = threadIdx.x;
    const int col = tid & 127;
    const int ty  = tid >> 7;
    const int rbase = blockIdx.x * 16;

    const float4* W4  = reinterpret_cast<const float4*>(Wm);
    float4*       Ws4 = reinterpret_cast<float4*>(Ws);
    #pragma unroll
    for (int i = 0; i < 16; ++i) Ws4[tid + i * 256] = W4[tid + i * 256];

    const float4* A4   = reinterpret_cast<const float4*>(src + (size_t)rbase * D);
    float4*       axs4 = reinterpret_cast<float4*>(axs);
    #pragma unroll
    for (int i = 0; i < 2; ++i) axs4[tid + i * 256] = A4[tid + i * 256];
    __syncthreads();

    float acc[8];
    #pragma unroll
    for (int i = 0; i < 8; ++i) acc[i] = 0.f;

    for (int k = 0; k < D; ++k) {
        float wv = Ws[k * D + col];
        #pragma unroll
        for (int i = 0; i < 8; ++i)
            acc[i] = fmaf(axs[(ty * 8 + i) * D + k], wv, acc[i]);
    }

    #pragma unroll
    for (int i = 0; i < 8; ++i)
        dst[(size_t)(rbase + ty * 8 + i) * D + col] = acc[i];
}

extern "C" void kernel_launch(void* const* d_in, const int* in_sizes, int n_in,
                              void* d_out, int out_size, void* d_ws, size_t ws_size,
                              hipStream_t stream) {
    const float* X     = (const float*)d_in[0];
    const int2*  edges = (const int2*)d_in[1];
    const float* wts   = (const float*)d_in[2];
    const float* Wm    = (const float*)d_in[3];
    float* out = (float*)d_out;
    char*  ws  = (char*)d_ws;

    const int eblocks = (NE + 255) / 256;

    if (ws_size >= NEED_NEW) {
        int2*  slab = (int2*)(ws + OFF_SLAB);
        int*   bcnt = (int*) (ws + OFF_BCNT);
        unsigned short* xw = (unsigned short*)(ws + OFF_XW);

        hipMemsetAsync(bcnt, 0, NB * NG * sizeof(int), stream);
        gc_gemm_bf16<<<NN / 16, 256, 0, stream>>>(X, xw, Wm);
        gc_bin<<<eblocks, 256, 0, stream>>>(edges, wts, bcnt, slab);
        gc_acc<<<NB, 256, 0, stream>>>(bcnt, slab, (const unsigned int*)xw, out);
    } else {
        int*  counts    = (int*) (ws + OFF_CNT);
        int*  row_start = (int*) (ws + OFF_ROW);
        int*  cursor    = (int*) (ws + OFF_CUR);
        int2* csr       = (int2*)(ws + OFF_CSR);

        hipMemsetAsync(counts, 0, NN * sizeof(int), stream);
        gc_hist<<<eblocks, 256, 0, stream>>>(edges, counts);
        gc_scan<<<1, 1024, 0, stream>>>(counts, row_start, cursor);
        gc_fill<<<eblocks, 256, 0, stream>>>(edges, wts, cursor, csr);
        gc_gather_f32<<<(NN * 64 + 255) / 256, 256, 0, stream>>>(row_start, csr, X, out);
        gc_gemm_f32<<<NN / 16, 256, 0, stream>>>(out, out, Wm);
    }
}

// Round 7
// 408.556 us; speedup vs baseline: 3.0547x; 3.0547x over previous
//
#include <hip/hip_runtime.h>
#include <hip/hip_fp16.h>

#define NN 50000
#define NE 800000
#define D  128

// ---- main-path ws layout (bytes) ----
#define OFF_CNT  0             // counts    int[NN]
#define OFF_ROW  200704        // row_start int[NN+1]
#define OFF_CUR  401408        // cursor    int[NN]
#define OFF_CSR4 602112        // csr4      uint[2E]      6.4 MB
#define OFF_XW   7002112       // XW bf16   ushort[NN*D] 12.8 MB
#define NEED_A   (OFF_XW + (size_t)NN * D * 2)   // ~19.8 MB

// ---- fallback ws layout ----
#define OFF_CSR8 602112        // int2[2E] 12.8 MB

__device__ __forceinline__ float bf_lo(unsigned int v) { return __uint_as_float(v << 16); }
__device__ __forceinline__ float bf_hi(unsigned int v) { return __uint_as_float(v & 0xffff0000u); }
__device__ __forceinline__ float wdec(unsigned int v) {
    return __half2float(__ushort_as_half((unsigned short)(v >> 16)));
}

// K1: per-edge histogram (both directions) — R3-proven standalone kernel
__global__ __launch_bounds__(256) void gc_hist(
    const int2* __restrict__ edges, int* __restrict__ counts)
{
    int e = blockIdx.x * 256 + threadIdx.x;
    if (e >= NE) return;
    int2 p = edges[e];
    atomicAdd(counts + p.x, 1);
    atomicAdd(counts + p.y, 1);
}

// K2: single-block exclusive scan of counts -> row_start, cursor
__global__ __launch_bounds__(1024) void gc_scan(
    const int* __restrict__ counts, int* __restrict__ row_start,
    int* __restrict__ cursor)
{
    const int CHUNK = (NN + 1023) / 1024;   // 49
    __shared__ int part[1024];
    int t = threadIdx.x;
    int lo = t * CHUNK, hi = min(lo + CHUNK, NN);
    int s = 0;
    for (int i = lo; i < hi; ++i) s += counts[i];
    part[t] = s;
    __syncthreads();
    for (int off = 1; off < 1024; off <<= 1) {
        int v = (t >= off) ? part[t - off] : 0;
        __syncthreads();
        part[t] += v;
        __syncthreads();
    }
    int run = part[t] - s;                  // exclusive prefix
    for (int i = lo; i < hi; ++i) {
        int c = counts[i];
        row_start[i] = run;
        cursor[i]    = run;
        run += c;
    }
    if (t == 1023) row_start[NN] = part[1023];
}

// K3: fill 4-byte CSR entries (col:16 | w_fp16:16) via per-node cursors.
__global__ __launch_bounds__(256) void gc_fill4(
    const int2* __restrict__ edges, const float* __restrict__ wts,
    int* __restrict__ cursor, unsigned int* __restrict__ csr4)
{
    int e = blockIdx.x * 256 + threadIdx.x;
    if (e >= NE) return;
    int2 p = edges[e];
    unsigned int hb = (unsigned int)__half_as_ushort(__float2half_rn(wts[e])) << 16;
    int pos = atomicAdd(cursor + p.y, 1);
    csr4[pos] = (unsigned int)p.x | hb;
    pos = atomicAdd(cursor + p.x, 1);
    csr4[pos] = (unsigned int)p.y | hb;
}

// K4: XW = X @ W, bf16 RNE output (packed). Block owns 16 rows; W in LDS.
__global__ __launch_bounds__(256) void gc_gemm_bf16(
    const float* __restrict__ src, unsigned short* __restrict__ dst,
    const float* __restrict__ Wm)
{
    __shared__ float Ws[D * D];
    __shared__ float axs[16 * D];
    const int tid = threadIdx.x;
    const int col = tid & 127;
    const int ty  = tid >> 7;
    const int rbase = blockIdx.x * 16;

    const float4* W4  = reinterpret_cast<const float4*>(Wm);
    float4*       Ws4 = reinterpret_cast<float4*>(Ws);
    #pragma unroll
    for (int i = 0; i < 16; ++i) Ws4[tid + i * 256] = W4[tid + i * 256];

    const float4* A4   = reinterpret_cast<const float4*>(src + (size_t)rbase * D);
    float4*       axs4 = reinterpret_cast<float4*>(axs);
    #pragma unroll
    for (int i = 0; i < 2; ++i) axs4[tid + i * 256] = A4[tid + i * 256];
    __syncthreads();

    float acc[8];
    #pragma unroll
    for (int i = 0; i < 8; ++i) acc[i] = 0.f;

    for (int k = 0; k < D; ++k) {
        float wv = Ws[k * D + col];
        #pragma unroll
        for (int i = 0; i < 8; ++i)
            acc[i] = fmaf(axs[(ty * 8 + i) * D + k], wv, acc[i]);
    }

    #pragma unroll
    for (int i = 0; i < 8; ++i) {
        unsigned int bb = __float_as_uint(acc[i]);
        unsigned int r  = (bb + 0x7fffu + ((bb >> 16) & 1u)) >> 16;   // RNE
        dst[(size_t)(rbase + ty * 8 + i) * D + col] = (unsigned short)r;
    }
}

// K5: gather bf16 rows, fused degree + normalization -> out (final).
__global__ __launch_bounds__(256) void gc_gather4(
    const int* __restrict__ row_start, const unsigned int* __restrict__ csr4,
    const unsigned int* __restrict__ F, float* __restrict__ out)
{
    int wid  = (blockIdx.x * 256 + threadIdx.x) >> 6;
    int lane = threadIdx.x & 63;
    if (wid >= NN) return;
    int j   = row_start[wid];
    int end = row_start[wid + 1];
    float ax = 0.f, ay = 0.f, dw = 0.f;
    for (; j + 4 <= end; j += 4) {
        unsigned int e0 = csr4[j], e1 = csr4[j + 1];
        unsigned int e2 = csr4[j + 2], e3 = csr4[j + 3];
        unsigned int v0 = F[(size_t)(e0 & 0xffffu) * 64 + lane];
        unsigned int v1 = F[(size_t)(e1 & 0xffffu) * 64 + lane];
        unsigned int v2 = F[(size_t)(e2 & 0xffffu) * 64 + lane];
        unsigned int v3 = F[(size_t)(e3 & 0xffffu) * 64 + lane];
        float w0 = wdec(e0), w1 = wdec(e1), w2 = wdec(e2), w3 = wdec(e3);
        ax = fmaf(w0, bf_lo(v0), ax); ay = fmaf(w0, bf_hi(v0), ay);
        ax = fmaf(w1, bf_lo(v1), ax); ay = fmaf(w1, bf_hi(v1), ay);
        ax = fmaf(w2, bf_lo(v2), ax); ay = fmaf(w2, bf_hi(v2), ay);
        ax = fmaf(w3, bf_lo(v3), ax); ay = fmaf(w3, bf_hi(v3), ay);
        dw += w0 + w1 + w2 + w3;
    }
    for (; j < end; ++j) {
        unsigned int e0 = csr4[j];
        unsigned int v0 = F[(size_t)(e0 & 0xffffu) * 64 + lane];
        float w0 = wdec(e0);
        ax = fmaf(w0, bf_lo(v0), ax); ay = fmaf(w0, bf_hi(v0), ay);
        dw += w0;
    }
    float inv = dw > 0.f ? 1.f / dw : 0.f;
    float2 r; r.x = ax * inv; r.y = ay * inv;
    reinterpret_cast<float2*>(out)[(size_t)wid * 64 + lane] = r;
}

// ======================= fallback path (fp32, small ws) ====================
__global__ __launch_bounds__(256) void gc_fill8(
    const int2* __restrict__ edges, const float* __restrict__ wts,
    int* __restrict__ cursor, int2* __restrict__ csr)
{
    int e = blockIdx.x * 256 + threadIdx.x;
    if (e >= NE) return;
    int2 p = edges[e];
    int wb = __float_as_int(wts[e]);
    int pos = atomicAdd(cursor + p.y, 1);
    csr[pos] = make_int2(p.x, wb);
    pos = atomicAdd(cursor + p.x, 1);
    csr[pos] = make_int2(p.y, wb);
}

__global__ __launch_bounds__(256) void gc_gather_f32(
    const int* __restrict__ row_start, const int2* __restrict__ csr,
    const float* __restrict__ F, float* __restrict__ out)
{
    int wid  = (blockIdx.x * 256 + threadIdx.x) >> 6;
    int lane = threadIdx.x & 63;
    if (wid >= NN) return;
    int j   = row_start[wid];
    int end = row_start[wid + 1];
    const float2* F2 = reinterpret_cast<const float2*>(F);
    float ax = 0.f, ay = 0.f, dw = 0.f;
    for (; j < end; ++j) {
        int2  cw = csr[j];
        float w  = __int_as_float(cw.y);
        float2 xv = F2[(size_t)cw.x * 64 + lane];
        ax = fmaf(w, xv.x, ax);
        ay = fmaf(w, xv.y, ay);
        dw += w;
    }
    float inv = dw > 0.f ? 1.f / dw : 0.f;
    float2 r; r.x = ax * inv; r.y = ay * inv;
    reinterpret_cast<float2*>(out)[(size_t)wid * 64 + lane] = r;
}

__global__ __launch_bounds__(256) void gc_gemm_f32(
    const float* __restrict__ src, float* __restrict__ dst,
    const float* __restrict__ Wm)
{
    __shared__ float Ws[D * D];
    __shared__ float axs[16 * D];
    const int tid = threadIdx.x;
    const int col = tid & 127;
    const int ty  = tid >> 7;
    const int rbase = blockIdx.x * 16;

    const float4* W4  = reinterpret_cast<const float4*>(Wm);
    float4*       Ws4 = reinterpret_cast<float4*>(Ws);
    #pragma unroll
    for (int i = 0; i < 16; ++i) Ws4[tid + i * 256] = W4[tid + i * 256];

    const float4* A4   = reinterpret_cast<const float4*>(src + (size_t)rbase * D);
    float4*       axs4 = reinterpret_cast<float4*>(axs);
    #pragma unroll
    for (int i = 0; i < 2; ++i) axs4[tid + i * 256] = A4[tid + i * 256];
    __syncthreads();

    float acc[8];
    #pragma unroll
    for (int i = 0; i < 8; ++i) acc[i] = 0.f;

    for (int k = 0; k < D; ++k) {
        float wv = Ws[k * D + col];
        #pragma unroll
        for (int i = 0; i < 8; ++i)
            acc[i] = fmaf(axs[(ty * 8 + i) * D + k], wv, acc[i]);
    }

    #pragma unroll
    for (int i = 0; i < 8; ++i)
        dst[(size_t)(rbase + ty * 8 + i) * D + col] = acc[i];
}

extern "C" void kernel_launch(void* const* d_in, const int* in_sizes, int n_in,
                              void* d_out, int out_size, void* d_ws, size_t ws_size,
                              hipStream_t stream) {
    const float* X     = (const float*)d_in[0];
    const int2*  edges = (const int2*)d_in[1];
    const float* wts   = (const float*)d_in[2];
    const float* Wm    = (const float*)d_in[3];
    float* out = (float*)d_out;
    char*  ws  = (char*)d_ws;

    int* counts    = (int*)(ws + OFF_CNT);
    int* row_start = (int*)(ws + OFF_ROW);
    int* cursor    = (int*)(ws + OFF_CUR);

    const int eblocks = (NE + 255) / 256;   // 3125
    hipMemsetAsync(counts, 0, NN * sizeof(int), stream);

    if (ws_size >= NEED_A) {
        unsigned int*   csr4 = (unsigned int*)(ws + OFF_CSR4);
        unsigned short* xw   = (unsigned short*)(ws + OFF_XW);

        gc_hist<<<eblocks, 256, 0, stream>>>(edges, counts);
        gc_scan<<<1, 1024, 0, stream>>>(counts, row_start, cursor);
        gc_fill4<<<eblocks, 256, 0, stream>>>(edges, wts, cursor, csr4);
        gc_gemm_bf16<<<NN / 16, 256, 0, stream>>>(X, xw, Wm);
        gc_gather4<<<(NN * 64 + 255) / 256, 256, 0, stream>>>(
            row_start, csr4, (const unsigned int*)xw, out);
    } else {
        int2* csr = (int2*)(ws + OFF_CSR8);
        gc_hist<<<eblocks, 256, 0, stream>>>(edges, counts);
        gc_scan<<<1, 1024, 0, stream>>>(counts, row_start, cursor);
        gc_fill8<<<eblocks, 256, 0, stream>>>(edges, wts, cursor, csr);
        gc_gather_f32<<<(NN * 64 + 255) / 256, 256, 0, stream>>>(row_start, csr, X, out);
        gc_gemm_f32<<<NN / 16, 256, 0, stream>>>(out, out, Wm);
    }
}